// Round 3
// baseline (22331.841 us; speedup 1.0000x reference)
//
#include <hip/hip_runtime.h>

#define TT 2048
#define BB 32
#define HH 512
#define NWG 32   // 32 WGs x 128 threads; WG g owns cols [g*16, g*16+16)

typedef _Float16 half8 __attribute__((ext_vector_type(8)));
typedef float f32x4 __attribute__((ext_vector_type(4)));

__device__ __forceinline__ float fsig(float x) { return 1.f / (1.f + __expf(-x)); }
__device__ __forceinline__ float ftanh_(float x) {
  x = fminf(fmaxf(x, -15.f), 15.f);
  float e = __expf(2.f * x);
  return (e - 1.f) / (e + 1.f);
}

// ---- fp32 -> fp16 convert, 4 elems/thread ----
__global__ void cvt_f32_f16(const float* __restrict__ in, _Float16* __restrict__ out, int n4) {
  int i = blockIdx.x * 256 + threadIdx.x;
  if (i >= n4) return;
  float4 v = ((const float4*)in)[i];
  union { _Float16 h[4]; unsigned long long u; } r;
  r.h[0] = (_Float16)v.x; r.h[1] = (_Float16)v.y;
  r.h[2] = (_Float16)v.z; r.h[3] = (_Float16)v.w;
  ((unsigned long long*)out)[i] = r.u;
}

// ---- phase 1: wx[bt][n] = sum_k x16[bt][k]*W16[n][k]; M=65536 N=2048 K=512 ----
__global__ __launch_bounds__(256, 2) void gemm_wx(const _Float16* __restrict__ A,
                                                  const _Float16* __restrict__ Bw,
                                                  _Float16* __restrict__ C) {
  const int bn = blockIdx.x;   // 0..15
  const int bm = blockIdx.y;   // 0..511
  const int tid = threadIdx.x;
  const int lane = tid & 63;
  const int w = tid >> 6;
  __shared__ _Float16 As[128 * 40];
  __shared__ _Float16 Bs[128 * 40];
  const int moff = (w & 1) * 64;
  const int noff = (w >> 1) * 64;
  const int fm = lane & 15;
  const int kq = lane >> 4;
  f32x4 acc[4][4] = {};
  for (int kt = 0; kt < 16; ++kt) {
#pragma unroll
    for (int e = 0; e < 2; ++e) {
      int ci = tid * 2 + e;
      int r = ci >> 2, c16 = ci & 3;
      half8 av = *(const half8*)(A + (size_t)(bm * 128 + r) * 512 + kt * 32 + c16 * 8);
      half8 bv = *(const half8*)(Bw + (size_t)(bn * 128 + r) * 512 + kt * 32 + c16 * 8);
      *(half8*)(As + r * 40 + c16 * 8) = av;
      *(half8*)(Bs + r * 40 + c16 * 8) = bv;
    }
    __syncthreads();
    half8 af[4], bf[4];
#pragma unroll
    for (int i = 0; i < 4; ++i) {
      af[i] = *(const half8*)(As + (moff + i * 16 + fm) * 40 + kq * 8);
      bf[i] = *(const half8*)(Bs + (noff + i * 16 + fm) * 40 + kq * 8);
    }
#pragma unroll
    for (int i = 0; i < 4; ++i)
#pragma unroll
      for (int j = 0; j < 4; ++j)
        acc[i][j] = __builtin_amdgcn_mfma_f32_16x16x32_f16(af[i], bf[j], acc[i][j], 0, 0, 0);
    __syncthreads();
  }
#pragma unroll
  for (int i = 0; i < 4; ++i) {
    int row = bm * 128 + moff + i * 16 + (lane >> 4) * 4;
#pragma unroll
    for (int j = 0; j < 4; ++j) {
      int col = bn * 128 + noff + j * 16 + (lane & 15);
#pragma unroll
      for (int r = 0; r < 4; ++r)
        C[(size_t)(row + r) * 2048 + col] = (_Float16)acc[i][j][r];
    }
  }
}

// ---- phase 2: persistent scan, barrier-free. 32 WGs x 128 threads. ----
// Wave (g, mi) owns: batches [mi*16, mi*16+16) x cols [g*16, g*16+16), ALL 4 gates.
// - gates for a (batch,col) land in ONE lane's 4 accs -> register elementwise,
//   no LDS, no __syncthreads anywhere.
// - h exchange: hexq[2][32][256] tagged u64 words {lo32 = 2x fp16 (col pair),
//   hi32 = step tag}. 128 KB total, always MALL-hot. Producers fire relaxed
//   agent 8B stores right after elementwise; consumers poll their own words
//   until all tags == t-1 (discovery == data transfer, one round trip).
// - skew < 2 slots: a wave passes its poll for step t only after ALL waves
//   published t, which (by data dependence) means all reads of slot t-1
//   completed -> safe to overwrite at t+1. Parity double-buffer suffices.
// - U streamed from L2 per step (compiler already does this in prior version).
__global__ __launch_bounds__(128, 1) void slstm_scan(
    const _Float16* __restrict__ wx,   // [B*T, 2048]
    const _Float16* __restrict__ U16,  // [2048, 512]
    const float* __restrict__ Wb, const float* __restrict__ Ub,
    const float* __restrict__ alpha,
    unsigned long long* __restrict__ hexq, // [2][32][256] tagged pairs (poisoned)
    float* __restrict__ out) {         // outs [32][2048][512] then h then c (fp32)
  const int g = blockIdx.x;
  const int tid = threadIdx.x;
  const int lane = tid & 63;
  const int mi = tid >> 6;        // wave = batch half
  const int nc = lane & 15;       // col-in-group AND A-row-in-tile
  const int kq = lane >> 4;       // k-quarter
  const int gcol = g * 16 + nc;   // this lane's h column
  const int b0 = mi * 16 + kq * 4;     // first of this lane's 4 C/D batches
  const int am = mi * 16 + nc;         // A-fragment batch row

  float bias[4];
#pragma unroll
  for (int q = 0; q < 4; ++q) bias[q] = Wb[q * 512 + gcol] + Ub[q * 512 + gcol];
  const float al = alpha[gcol];
  float c[4] = {0.f, 0.f, 0.f, 0.f};

  const _Float16* wxb[4];
#pragma unroll
  for (int i = 0; i < 4; ++i)
    wxb[i] = wx + (size_t)(b0 + i) * TT * 2048 + gcol;

  // B-fragment base: row (q*512 + gcol), k-slice kq  (streamed from L2 per step)
  const _Float16* ub = U16 + (size_t)gcol * 512 + kq * 8;

  int budget = 1 << 22;  // poll-round safety valve vs. eternal hang

  for (int t = 0; t < TT; ++t) {
    // wx prefetch: 16 scalar fp16 loads, independent of h, hidden under poll+MFMA
    _Float16 wxv[4][4];
#pragma unroll
    for (int i = 0; i < 4; ++i)
#pragma unroll
      for (int q = 0; q < 4; ++q)
        wxv[i][q] = wxb[i][(size_t)t * 2048 + q * 512];

    f32x4 acc[4] = {};
    if (t > 0) {
      const unsigned exp_tag = (unsigned)(t - 1);
      const unsigned long long* hb =
          hexq + (((t - 1) & 1) ? 8192 : 0) + (size_t)am * 256;
      union { unsigned u[4]; half8 h; } af[16];
      unsigned bad;
      do {
        bad = 0;
#pragma unroll
        for (int ks = 0; ks < 16; ++ks) {
#pragma unroll
          for (int p = 0; p < 4; ++p) {
            unsigned long long wv = __hip_atomic_load(
                hb + ks * 16 + kq * 4 + p, __ATOMIC_RELAXED, __HIP_MEMORY_SCOPE_AGENT);
            bad |= ((unsigned)(wv >> 32)) ^ exp_tag;
            af[ks].u[p] = (unsigned)wv;
          }
        }
      } while (__any(bad != 0) && --budget > 0);
      // 4 gate chains x 16 k-steps; B streamed (loads pipeline ahead of MFMAs)
#pragma unroll
      for (int ks = 0; ks < 16; ++ks) {
#pragma unroll
        for (int q = 0; q < 4; ++q) {
          half8 bf = *(const half8*)(ub + (size_t)q * 512 * 512 + ks * 32);
          acc[q] = __builtin_amdgcn_mfma_f32_16x16x32_f16(af[ks].h, bf, acc[q], 0, 0, 0);
        }
      }
    }
    // elementwise: 4 batches x 1 col per lane, all gates in registers
    float h[4];
#pragma unroll
    for (int i = 0; i < 4; ++i) {
      float pi = acc[0][i] + (float)wxv[i][0] + bias[0];
      float pf = acc[1][i] + (float)wxv[i][1] + bias[1];
      float po = acc[2][i] + (float)wxv[i][2] + bias[2];
      float pg = acc[3][i] + (float)wxv[i][3] + bias[3];
      float ig = fsig(pi), fg = fsig(pf), og = fsig(po), gg = ftanh_(pg);
      c[i] = al * (fg * c[i] + ig * gg);
      h[i] = og * ftanh_(c[i]);
    }
    // publish: pair adjacent cols via shfl_xor(1); 2 tagged 8B stores per lane
    union { _Float16 hh[2]; unsigned u; } pk01, pk23;
    pk01.hh[0] = (_Float16)h[0]; pk01.hh[1] = (_Float16)h[1];
    pk23.hh[0] = (_Float16)h[2]; pk23.hh[1] = (_Float16)h[3];
    unsigned sw01 = (unsigned)__shfl_xor((int)pk01.u, 1);
    unsigned sw23 = (unsigned)__shfl_xor((int)pk23.u, 1);
    unsigned wA, wB; int bA, bB;
    if ((lane & 1) == 0) {        // even col: own value in low half of the pair
      wA = (pk01.u & 0xffffu) | ((sw01 & 0xffffu) << 16); bA = b0 + 0;
      wB = (pk01.u >> 16)     | (sw01 & 0xffff0000u);     bB = b0 + 1;
    } else {                      // odd col: own value in high half
      wA = (sw23 & 0xffffu) | ((pk23.u & 0xffffu) << 16); bA = b0 + 2;
      wB = (sw23 >> 16)     | (pk23.u & 0xffff0000u);     bB = b0 + 3;
    }
    const int cp = g * 8 + (nc >> 1);
    unsigned long long* hw = hexq + ((t & 1) ? 8192 : 0);
    const unsigned long long tagv = ((unsigned long long)(unsigned)t) << 32;
    __hip_atomic_store(hw + (size_t)bA * 256 + cp, tagv | wA,
                       __ATOMIC_RELAXED, __HIP_MEMORY_SCOPE_AGENT);
    __hip_atomic_store(hw + (size_t)bB * 256 + cp, tagv | wB,
                       __ATOMIC_RELAXED, __HIP_MEMORY_SCOPE_AGENT);
    // outputs (off the critical path)
#pragma unroll
    for (int i = 0; i < 4; ++i)
      __builtin_nontemporal_store(h[i], out + ((size_t)(b0 + i) * TT + t) * HH + gcol);
    if (t == TT - 1) {
      const size_t HB = (size_t)BB * TT * HH;
#pragma unroll
      for (int i = 0; i < 4; ++i) {
        out[HB + (size_t)(b0 + i) * HH + gcol] = h[i];
        out[HB + (size_t)BB * HH + (size_t)(b0 + i) * HH + gcol] = c[i];
      }
    }
  }
}

extern "C" void kernel_launch(void* const* d_in, const int* in_sizes, int n_in,
                              void* d_out, int out_size, void* d_ws, size_t ws_size,
                              hipStream_t stream) {
  (void)in_sizes; (void)n_in; (void)out_size; (void)ws_size;
  const float* x  = (const float*)d_in[0];
  const float* Ww = (const float*)d_in[1];
  const float* Wb = (const float*)d_in[2];
  const float* Uw = (const float*)d_in[3];
  const float* Ub = (const float*)d_in[4];
  const float* al = (const float*)d_in[5];
  float* out = (float*)d_out;

  char* p = (char*)d_ws;
  _Float16* x16  = (_Float16*)p; p += (size_t)BB * TT * 512 * 2;   // 64 MiB
  _Float16* wx16 = (_Float16*)p; p += (size_t)BB * TT * 2048 * 2;  // 256 MiB
  _Float16* U16  = (_Float16*)p; p += (size_t)2048 * 512 * 2;
  _Float16* W16  = (_Float16*)p; p += (size_t)2048 * 512 * 2;
  unsigned long long* hexq = (unsigned long long*)p;               // [2][32][256] = 128 KiB
  p += (size_t)2 * 32 * 256 * 8;

  cvt_f32_f16<<<32768, 256, 0, stream>>>(x, x16, BB * TT * 512 / 4);
  cvt_f32_f16<<<1024, 256, 0, stream>>>(Ww, W16, 2048 * 512 / 4);
  cvt_f32_f16<<<1024, 256, 0, stream>>>(Uw, U16, 2048 * 512 / 4);
  gemm_wx<<<dim3(16, 512), 256, 0, stream>>>(x16, W16, wx16);
  // poison the exchange so stale tags can never match step 0
  (void)hipMemsetAsync(hexq, 0xFF, (size_t)2 * 32 * 256 * 8, stream);
  slstm_scan<<<NWG, 128, 0, stream>>>(wx16, U16, Wb, Ub, al, hexq, out);
}